// Round 1
// baseline (430.561 us; speedup 1.0000x reference)
//
#include <hip/hip_runtime.h>

#define BB   64
#define CC   64
#define NSP  12544     // 112*112
#define NSP4 3136      // NSP/4
#define BC   (BB*CC)   // 4096
#define KCL  8
#define TILES ((NSP4 + 255) / 256)   // 13

// ---------------- Kernel 1: per-(b,c) sum and sumsq over H*W ----------------
__global__ __launch_bounds__(256) void reduce_kernel(
    const float4* __restrict__ x, double* __restrict__ s1, double* __restrict__ s2)
{
    const int bc = blockIdx.x;
    const int t  = threadIdx.x;
    const float4* p = x + (size_t)bc * NSP4;

    double a1 = 0.0, a2 = 0.0;
    for (int i = t; i < NSP4; i += 256) {
        float4 v = p[i];
        a1 += (double)v.x + (double)v.y + (double)v.z + (double)v.w;
        a2 += (double)v.x * v.x + (double)v.y * v.y
            + (double)v.z * v.z + (double)v.w * v.w;
    }

    __shared__ double sh1[256];
    __shared__ double sh2[256];
    sh1[t] = a1; sh2[t] = a2;
    __syncthreads();
    for (int s = 128; s > 0; s >>= 1) {
        if (t < s) { sh1[t] += sh1[t + s]; sh2[t] += sh2[t + s]; }
        __syncthreads();
    }
    if (t == 0) { s1[bc] = sh1[0]; s2[bc] = sh2[0]; }
}

// ---------------- Kernel 2: cluster stats -> per-(b,c) scale/bias ----------------
__global__ __launch_bounds__(256) void stats_kernel(
    const double* __restrict__ s1, const double* __restrict__ s2,
    const float* __restrict__ cluster_map,   // [B,K] (leading 1 dropped)
    const float* __restrict__ lmda,          // [B]
    float* __restrict__ A, float* __restrict__ Bias)
{
    const int t = threadIdx.x;

    __shared__ int    cid[BB];
    __shared__ float  counts[KCL];
    __shared__ double cs1[KCL * CC];
    __shared__ double cs2[KCL * CC];

    // hard cluster assignment: argmax over K (first-max wins, matches jnp.argmax)
    if (t < BB) {
        float best = cluster_map[t * KCL];
        int   bi   = 0;
        for (int k = 1; k < KCL; k++) {
            float v = cluster_map[t * KCL + k];
            if (v > best) { best = v; bi = k; }
        }
        cid[t] = bi;
    }
    __syncthreads();

    if (t < KCL) {
        int cnt = 0;
        for (int b = 0; b < BB; b++) if (cid[b] == t) cnt++;
        counts[t] = (float)cnt;
    }
    if (t < CC) {
        double a1[KCL], a2[KCL];
        for (int k = 0; k < KCL; k++) { a1[k] = 0.0; a2[k] = 0.0; }
        for (int b = 0; b < BB; b++) {
            int k = cid[b];
            a1[k] += s1[b * CC + t];
            a2[k] += s2[b * CC + t];
        }
        for (int k = 0; k < KCL; k++) {
            cs1[k * CC + t] = a1[k];
            cs2[k * CC + t] = a2[k];
        }
    }
    __syncthreads();

    for (int i = t; i < BC; i += 256) {
        const int b = i >> 6;
        const int c = i & 63;

        double sm  = s1[i] / (double)NSP;
        double sv  = (s2[i] - (double)NSP * sm * sm) / (double)(NSP - 1);
        float  smu  = (float)sm;
        float  sstd = sqrtf((float)sv + 1e-6f);

        int    k   = cid[b];
        double nk  = fmax((double)counts[k] * (double)NSP, 1.0);
        double cm  = cs1[k * CC + c] / nk;
        double cv  = (cs2[k * CC + c] - nk * cm * cm) / fmax(nk - 1.0, 1.0);
        float  cmu  = (float)cm;
        float  cstd = sqrtf((float)cv + 1e-6f);

        float l = lmda[b];
        float mu_mix  = smu  * l + cmu  * (1.0f - l);
        float std_mix = sstd * l + cstd * (1.0f - l);
        float a = std_mix / sstd;
        A[i]    = a;
        Bias[i] = mu_mix - smu * a;
    }
}

// ---------------- Kernel 3: out = x * A[bc] + Bias[bc] ----------------
__global__ __launch_bounds__(256) void apply_kernel(
    const float4* __restrict__ x, const float* __restrict__ A,
    const float* __restrict__ Bias, float4* __restrict__ out)
{
    const int bc = blockIdx.x;
    const int i  = blockIdx.y * 256 + threadIdx.x;
    const float a  = A[bc];
    const float bb = Bias[bc];
    if (i < NSP4) {
        const size_t off = (size_t)bc * NSP4 + i;
        float4 v = x[off];
        float4 o;
        o.x = fmaf(v.x, a, bb);
        o.y = fmaf(v.y, a, bb);
        o.z = fmaf(v.z, a, bb);
        o.w = fmaf(v.w, a, bb);
        out[off] = o;
    }
}

extern "C" void kernel_launch(void* const* d_in, const int* in_sizes, int n_in,
                              void* d_out, int out_size, void* d_ws, size_t ws_size,
                              hipStream_t stream)
{
    const float* x  = (const float*)d_in[0];   // [64,64,112,112]
    const float* cm = (const float*)d_in[1];   // [1,64,8]
    const float* lm = (const float*)d_in[2];   // [64,1,1,1]
    float* out = (float*)d_out;

    double* s1   = (double*)d_ws;              // 4096 doubles
    double* s2   = s1 + BC;                    // 4096 doubles
    float*  A    = (float*)(s2 + BC);          // 4096 floats
    float*  Bias = A + BC;                     // 4096 floats

    reduce_kernel<<<BC, 256, 0, stream>>>((const float4*)x, s1, s2);
    stats_kernel<<<1, 256, 0, stream>>>(s1, s2, cm, lm, A, Bias);
    apply_kernel<<<dim3(BC, TILES), 256, 0, stream>>>((const float4*)x, A, Bias, (float4*)out);
}

// Round 2
// 387.553 us; speedup vs baseline: 1.1110x; 1.1110x over previous
//
#include <hip/hip_runtime.h>

#define BB   64
#define CC   64
#define NSP  12544     // 112*112
#define NSP4 3136      // NSP/4
#define BC   (BB*CC)   // 4096
#define KCL  8

typedef float f32x4 __attribute__((ext_vector_type(4)));

// ---------------- Kernel 1: per-(b,c) sum and sumsq over H*W ----------------
// One block per (b,c). 256 threads, fp32 partials (52 elems/thread), wave
// shuffle reduction, tiny LDS combine. Default (cached) loads so x lands in
// L3 for the apply pass.
__global__ __launch_bounds__(256) void reduce_kernel(
    const f32x4* __restrict__ x, float* __restrict__ s1, float* __restrict__ s2)
{
    const int bc = blockIdx.x;
    const int t  = threadIdx.x;
    const f32x4* p = x + (size_t)bc * NSP4;

    float a1 = 0.0f, a2 = 0.0f;
    for (int i = t; i < NSP4; i += 256) {
        f32x4 v = p[i];
        a1 += v.x + v.y + v.z + v.w;
        a2 += v.x * v.x + v.y * v.y + v.z * v.z + v.w * v.w;
    }

    // 64-lane wave reduction
    for (int off = 32; off > 0; off >>= 1) {
        a1 += __shfl_down(a1, off, 64);
        a2 += __shfl_down(a2, off, 64);
    }

    __shared__ float w1[4], w2[4];
    const int wid = t >> 6;
    if ((t & 63) == 0) { w1[wid] = a1; w2[wid] = a2; }
    __syncthreads();
    if (t == 0) {
        s1[bc] = (w1[0] + w1[1]) + (w1[2] + w1[3]);
        s2[bc] = (w2[0] + w2[1]) + (w2[2] + w2[3]);
    }
}

// ---------------- Kernel 2: cluster stats -> per-(b,c) scale/bias ----------------
// Single block; all cluster accumulation in LDS (no runtime-indexed private
// arrays -> no scratch).
__global__ __launch_bounds__(256) void stats_kernel(
    const float* __restrict__ s1, const float* __restrict__ s2,
    const float* __restrict__ cluster_map,   // [B,K]
    const float* __restrict__ lmda,          // [B]
    float* __restrict__ A, float* __restrict__ Bias)
{
    const int t = threadIdx.x;

    __shared__ int    cid[BB];
    __shared__ float  counts[KCL];
    __shared__ double cs1[KCL * CC];
    __shared__ double cs2[KCL * CC];

    // hard cluster assignment: argmax over K (first-max wins)
    if (t < BB) {
        float best = cluster_map[t * KCL];
        int   bi   = 0;
        for (int k = 1; k < KCL; k++) {
            float v = cluster_map[t * KCL + k];
            if (v > best) { best = v; bi = k; }
        }
        cid[t] = bi;
    }
    __syncthreads();

    if (t < KCL) {
        int cnt = 0;
        for (int b = 0; b < BB; b++) if (cid[b] == t) cnt++;
        counts[t] = (float)cnt;
    }
    if (t < CC) {
        // zero my column across all clusters
        for (int k = 0; k < KCL; k++) { cs1[k * CC + t] = 0.0; cs2[k * CC + t] = 0.0; }
        for (int b = 0; b < BB; b++) {
            int k = cid[b];
            cs1[k * CC + t] += (double)s1[b * CC + t];
            cs2[k * CC + t] += (double)s2[b * CC + t];
        }
    }
    __syncthreads();

    for (int i = t; i < BC; i += 256) {
        const int b = i >> 6;
        const int c = i & 63;

        float sm   = s1[i] * (1.0f / NSP);
        float sv   = (s2[i] - (float)NSP * sm * sm) * (1.0f / (NSP - 1));
        float smu  = sm;
        float sstd = sqrtf(sv + 1e-6f);

        int    k   = cid[b];
        double nk  = fmax((double)counts[k] * (double)NSP, 1.0);
        double cm  = cs1[k * CC + c] / nk;
        double cv  = (cs2[k * CC + c] - nk * cm * cm) / fmax(nk - 1.0, 1.0);
        float  cmu  = (float)cm;
        float  cstd = sqrtf((float)cv + 1e-6f);

        float l = lmda[b];
        float mu_mix  = smu  * l + cmu  * (1.0f - l);
        float std_mix = sstd * l + cstd * (1.0f - l);
        float a = std_mix / sstd;
        A[i]    = a;
        Bias[i] = mu_mix - smu * a;
    }
}

// ---------------- Kernel 3: out = x * A[bc] + Bias[bc] ----------------
// One block per (b,c); A/Bias are wave-uniform (scalar loads), 13 tiles per
// block. Non-temporal stores keep x resident in L3 for the in-flight reads.
__global__ __launch_bounds__(256) void apply_kernel(
    const f32x4* __restrict__ x, const float* __restrict__ A,
    const float* __restrict__ Bias, f32x4* __restrict__ out)
{
    const int bc = blockIdx.x;
    const int t  = threadIdx.x;
    const float a  = A[bc];
    const float bb = Bias[bc];
    const size_t base = (size_t)bc * NSP4;

    for (int i = t; i < NSP4; i += 256) {
        f32x4 v = x[base + i];
        f32x4 o;
        o.x = fmaf(v.x, a, bb);
        o.y = fmaf(v.y, a, bb);
        o.z = fmaf(v.z, a, bb);
        o.w = fmaf(v.w, a, bb);
        __builtin_nontemporal_store(o, &out[base + i]);
    }
}

extern "C" void kernel_launch(void* const* d_in, const int* in_sizes, int n_in,
                              void* d_out, int out_size, void* d_ws, size_t ws_size,
                              hipStream_t stream)
{
    const float* x  = (const float*)d_in[0];   // [64,64,112,112]
    const float* cm = (const float*)d_in[1];   // [1,64,8]
    const float* lm = (const float*)d_in[2];   // [64,1,1,1]
    float* out = (float*)d_out;

    float* s1   = (float*)d_ws;                // 4096 floats
    float* s2   = s1 + BC;                     // 4096 floats
    float* A    = s2 + BC;                     // 4096 floats
    float* Bias = A + BC;                      // 4096 floats

    reduce_kernel<<<BC, 256, 0, stream>>>((const f32x4*)x, s1, s2);
    stats_kernel<<<1, 256, 0, stream>>>(s1, s2, cm, lm, A, Bias);
    apply_kernel<<<BC, 256, 0, stream>>>((const f32x4*)x, A, Bias, (f32x4*)out);
}